// Round 5
// baseline (320.169 us; speedup 1.0000x reference)
//
#include <hip/hip_runtime.h>
#include <hip/hip_bf16.h>
#include <math.h>

// DistMult edge scoring: out[e] = sigmoid(sum_d h[u[e],d] * rel[etype[e],d] * h[v[e],d])
// N_NODES=100000, E=250000, D=384, N_ETYPES=8.
// Inputs: h (fp32), u (int32), v (int32), etype (int32), rel_weight (fp32). Out: fp32 [E].
//
// R4: gather walls measured so far: HBM-random ~3.05 TB/s, IF$-random ~4.7 TB/s,
// latency-insensitive (R3). Attack bytes: counting-sort edges into u-buckets
// (32 rows / 24 KB bf16 window) so u-row reuse (avg 2.5 edges/row) is served
// by L2 instead of the IF$ fabric; XCD swizzle keeps bucket runs L2-local.
// Pipeline: zero-hist | conv h->bf16 | conv rel | hist | scan | scatter | main.

#define D 384
#define N_NODES 100000
#define N_NODES_ELEMS (N_NODES * D)
#define H_BF16_BYTES  (N_NODES * D * 2)       // 76,800,000 B
#define BUCKET_SHIFT 5
#define N_BUCKETS ((N_NODES + 31) >> BUCKET_SHIFT)   // 3125
#define SCAN_SIZE 4096                         // padded scan width (1024 thr x 4)

// ---- workspace layout ----
// [0, 76800000)                bf16 h
// [76800000, 76806144)         bf16 rel
// [76806144, +4096*4)          hist / offsets
// [76822528, +4096*4)          cursors
// [76838912, +250000*16)       sorted edge records (u,v,etype,orig)
#define WS_RB_OFF   76800000
#define WS_HIST_OFF 76806144
#define WS_CUR_OFF  76822528
#define WS_REC_OFF  76838912

__global__ __launch_bounds__(1024) void zero_hist_kernel(uint32_t* __restrict__ hist)
{
    int t = threadIdx.x;
#pragma unroll
    for (int i = 0; i < 4; ++i)
        hist[t * 4 + i] = 0u;
}

// fp32 -> packed bf16, 8 floats / thread
__global__ __launch_bounds__(256) void conv_kernel(
    const float* __restrict__ src, uint32_t* __restrict__ dst, int n8)
{
    int i = blockIdx.x * blockDim.x + threadIdx.x;
    if (i >= n8) return;
    const float4* s = (const float4*)(src) + (size_t)i * 2;
    float4 f0 = s[0];
    float4 f1 = s[1];
    uint4 o;
    o.x = (uint32_t)__bfloat16_as_ushort(__float2bfloat16(f0.x)) |
          ((uint32_t)__bfloat16_as_ushort(__float2bfloat16(f0.y)) << 16);
    o.y = (uint32_t)__bfloat16_as_ushort(__float2bfloat16(f0.z)) |
          ((uint32_t)__bfloat16_as_ushort(__float2bfloat16(f0.w)) << 16);
    o.z = (uint32_t)__bfloat16_as_ushort(__float2bfloat16(f1.x)) |
          ((uint32_t)__bfloat16_as_ushort(__float2bfloat16(f1.y)) << 16);
    o.w = (uint32_t)__bfloat16_as_ushort(__float2bfloat16(f1.z)) |
          ((uint32_t)__bfloat16_as_ushort(__float2bfloat16(f1.w)) << 16);
    ((uint4*)dst)[i] = o;
}

__global__ __launch_bounds__(256) void hist_kernel(
    const int* __restrict__ u, uint32_t* __restrict__ hist, int n_edges)
{
    int e = blockIdx.x * blockDim.x + threadIdx.x;
    if (e >= n_edges) return;
    atomicAdd(&hist[(uint32_t)u[e] >> BUCKET_SHIFT], 1u);
}

// single-block exclusive scan over SCAN_SIZE bins; writes offsets AND cursors
__global__ __launch_bounds__(1024) void scan_kernel(
    const uint32_t* __restrict__ hist,
    uint32_t* __restrict__ offsets,
    uint32_t* __restrict__ cursors)
{
    __shared__ uint32_t tmp[1024];
    int t = threadIdx.x;
    uint32_t v0 = hist[t * 4 + 0];
    uint32_t v1 = hist[t * 4 + 1];
    uint32_t v2 = hist[t * 4 + 2];
    uint32_t v3 = hist[t * 4 + 3];
    tmp[t] = v0 + v1 + v2 + v3;
    __syncthreads();
    // Hillis-Steele inclusive scan over 1024 partials
#pragma unroll
    for (int off = 1; off < 1024; off <<= 1) {
        uint32_t x = (t >= off) ? tmp[t - off] : 0u;
        __syncthreads();
        tmp[t] += x;
        __syncthreads();
    }
    uint32_t base = (t == 0) ? 0u : tmp[t - 1];
    uint32_t o0 = base;
    uint32_t o1 = o0 + v0;
    uint32_t o2 = o1 + v1;
    uint32_t o3 = o2 + v2;
    offsets[t * 4 + 0] = o0; cursors[t * 4 + 0] = o0;
    offsets[t * 4 + 1] = o1; cursors[t * 4 + 1] = o1;
    offsets[t * 4 + 2] = o2; cursors[t * 4 + 2] = o2;
    offsets[t * 4 + 3] = o3; cursors[t * 4 + 3] = o3;
}

__global__ __launch_bounds__(256) void scatter_kernel(
    const int* __restrict__ u, const int* __restrict__ v,
    const int* __restrict__ etype,
    uint32_t* __restrict__ cursors, uint4* __restrict__ rec, int n_edges)
{
    int e = blockIdx.x * blockDim.x + threadIdx.x;
    if (e >= n_edges) return;
    uint32_t uu = (uint32_t)u[e];
    uint32_t pos = atomicAdd(&cursors[uu >> BUCKET_SHIFT], 1u);
    rec[pos] = make_uint4(uu, (uint32_t)v[e], (uint32_t)etype[e], (uint32_t)e);
}

// main pass: 8 lanes/edge over bucket-sorted records, XCD-contiguous swizzle
__global__ __launch_bounds__(256) void distmult_kernel(
    const uint32_t* __restrict__ hb,   // bf16-packed h [N_NODES][192]
    const uint32_t* __restrict__ rb,   // bf16-packed rel [8][192]
    const uint4* __restrict__ rec,
    float* __restrict__ out,
    int n_edges, int grid_main)
{
    // map round-robin XCD assignment (bid % 8) to contiguous edge ranges
    int p = blockIdx.x;
    int gp = grid_main & ~7;           // largest multiple of 8
    int lb;
    if (p < gp) lb = (p & 7) * (gp >> 3) + (p >> 3);
    else        lb = p;

    int tid  = lb * blockDim.x + threadIdx.x;
    int s    = tid >> 3;               // sorted edge index, 8 lanes/edge
    int lane = threadIdx.x & 7;
    if (s >= n_edges) return;

    uint4 r4 = rec[s];                 // broadcast within the 8-lane group
    const uint4* hu = (const uint4*)(hb + (size_t)r4.x * (D / 2));
    const uint4* hv = (const uint4*)(hb + (size_t)r4.y * (D / 2));
    const uint4* rr = (const uint4*)(rb + (size_t)r4.z * (D / 2));

    uint4 a[6], b[6], c[6];
#pragma unroll
    for (int k = 0; k < 6; ++k) {
        int j = lane + k * 8;          // 48 uint4 per row / 8 lanes
        a[k] = hu[j];
        b[k] = hv[j];
        c[k] = rr[j];
    }

    float sc = 0.0f;
#pragma unroll
    for (int k = 0; k < 6; ++k) {
        const uint32_t* pa = &a[k].x;
        const uint32_t* pb = &b[k].x;
        const uint32_t* pc = &c[k].x;
#pragma unroll
        for (int q = 0; q < 4; ++q) {
            float alo = __uint_as_float(pa[q] << 16);
            float ahi = __uint_as_float(pa[q] & 0xffff0000u);
            float blo = __uint_as_float(pb[q] << 16);
            float bhi = __uint_as_float(pb[q] & 0xffff0000u);
            float clo = __uint_as_float(pc[q] << 16);
            float chi = __uint_as_float(pc[q] & 0xffff0000u);
            sc += alo * clo * blo;
            sc += ahi * chi * bhi;
        }
    }

#pragma unroll
    for (int off = 4; off >= 1; off >>= 1)
        sc += __shfl_xor(sc, off);

    if (lane == 0)
        out[r4.w] = 1.0f / (1.0f + __expf(-sc));
}

extern "C" void kernel_launch(void* const* d_in, const int* in_sizes, int n_in,
                              void* d_out, int out_size, void* d_ws, size_t ws_size,
                              hipStream_t stream) {
    const float* h     = (const float*)d_in[0];
    const int*   u     = (const int*)  d_in[1];
    const int*   v     = (const int*)  d_in[2];
    const int*   etype = (const int*)  d_in[3];
    const float* rel   = (const float*)d_in[4];
    float* out = (float*)d_out;

    int n_edges = in_sizes[1];          // 250000
    int n_rel   = in_sizes[4];          // 3072

    char* ws = (char*)d_ws;
    uint32_t* hb      = (uint32_t*)ws;
    uint32_t* rb      = (uint32_t*)(ws + WS_RB_OFF);
    uint32_t* hist    = (uint32_t*)(ws + WS_HIST_OFF);
    uint32_t* cursors = (uint32_t*)(ws + WS_CUR_OFF);
    uint4*    rec     = (uint4*)   (ws + WS_REC_OFF);

    // sort prologue (overlaps nothing; all tiny)
    zero_hist_kernel<<<1, 1024, 0, stream>>>(hist);
    int n8_h = N_NODES_ELEMS / 8;
    conv_kernel<<<(n8_h + 255) / 256, 256, 0, stream>>>(h, hb, n8_h);
    int n8_r = n_rel / 8;
    conv_kernel<<<(n8_r + 255) / 256, 256, 0, stream>>>(rel, rb, n8_r);
    hist_kernel<<<(n_edges + 255) / 256, 256, 0, stream>>>(u, hist, n_edges);
    scan_kernel<<<1, 1024, 0, stream>>>(hist, hist /*offsets in-place ok: reads then writes same idx*/, cursors);
    scatter_kernel<<<(n_edges + 255) / 256, 256, 0, stream>>>(u, v, etype, cursors, rec, n_edges);

    long long threads_total = (long long)n_edges * 8;
    int grid_main = (int)((threads_total + 255) / 256);
    distmult_kernel<<<grid_main, 256, 0, stream>>>(hb, rb, rec, out, n_edges, grid_main);
}

// Round 6
// 277.090 us; speedup vs baseline: 1.1555x; 1.1555x over previous
//
#include <hip/hip_runtime.h>
#include <hip/hip_bf16.h>
#include <math.h>

// DistMult edge scoring: out[e] = sigmoid(sum_d h[u[e],d] * rel[etype[e],d] * h[v[e],d])
// N_NODES=100000, E=250000, D=384, N_ETYPES=8.
// Inputs: h (fp32), u (int32), v (int32), etype (int32), rel_weight (fp32). Out: fp32 [E].
//
// R5 = revert to R2 (best measured: 278.8 us total).
// Established walls (R0-R4): random 128B-line L2-miss path ~3 TB/s chip-wide,
// insensitive to MLP depth (R1 vs R3), segment width (R2 vs R3), and locality
// sorting (R4: +40 us, main unchanged). bf16 shadow halves miss bytes for a
// 37 us conv cost (conv streams at the ~10 B/cy/CU cap) -> net best.
// fp8 rejected on accuracy (threshold 2e-2, est. absmax ~2e-2+).

#define D 384
#define N_NODES_ELEMS (100000 * 384)          // h element count
#define H_BF16_BYTES  (100000 * 384 * 2)      // 76,800,000 (16B aligned)

// ---- pass 1: fp32 -> packed bf16, 8 floats / thread ----
__global__ __launch_bounds__(256) void conv_kernel(
    const float* __restrict__ src, uint32_t* __restrict__ dst, int n8)
{
    int i = blockIdx.x * blockDim.x + threadIdx.x;
    if (i >= n8) return;
    const float4* s = (const float4*)(src) + (size_t)i * 2;
    float4 f0 = s[0];
    float4 f1 = s[1];
    uint4 o;
    o.x = (uint32_t)__bfloat16_as_ushort(__float2bfloat16(f0.x)) |
          ((uint32_t)__bfloat16_as_ushort(__float2bfloat16(f0.y)) << 16);
    o.y = (uint32_t)__bfloat16_as_ushort(__float2bfloat16(f0.z)) |
          ((uint32_t)__bfloat16_as_ushort(__float2bfloat16(f0.w)) << 16);
    o.z = (uint32_t)__bfloat16_as_ushort(__float2bfloat16(f1.x)) |
          ((uint32_t)__bfloat16_as_ushort(__float2bfloat16(f1.y)) << 16);
    o.w = (uint32_t)__bfloat16_as_ushort(__float2bfloat16(f1.z)) |
          ((uint32_t)__bfloat16_as_ushort(__float2bfloat16(f1.w)) << 16);
    ((uint4*)dst)[i] = o;
}

// ---- pass 2: gather bf16 rows, 16 lanes/edge, 3 uint4 per operand per lane ----
__global__ __launch_bounds__(256) void distmult_kernel(
    const uint32_t* __restrict__ hb,   // bf16-packed h [N_NODES][192 uints]
    const uint32_t* __restrict__ rb,   // bf16-packed rel [8][192]
    const int* __restrict__ u,
    const int* __restrict__ v,
    const int* __restrict__ etype,
    float* __restrict__ out,
    int n_edges)
{
    int tid  = blockIdx.x * blockDim.x + threadIdx.x;
    int e    = tid >> 4;
    int lane = threadIdx.x & 15;
    if (e >= n_edges) return;

    const uint4* hu = (const uint4*)(hb + (size_t)u[e]     * (D / 2));
    const uint4* hv = (const uint4*)(hb + (size_t)v[e]     * (D / 2));
    const uint4* r  = (const uint4*)(rb + (size_t)etype[e] * (D / 2));

    uint4 a[3], b[3], c[3];
#pragma unroll
    for (int k = 0; k < 3; ++k) {
        int j = lane + k * 16;     // 48 uint4 per row / 16 lanes = 3
        a[k] = hu[j];
        b[k] = hv[j];
        c[k] = r[j];
    }

    float s = 0.0f;
#pragma unroll
    for (int k = 0; k < 3; ++k) {
        const uint32_t* pa = &a[k].x;
        const uint32_t* pb = &b[k].x;
        const uint32_t* pc = &c[k].x;
#pragma unroll
        for (int q = 0; q < 4; ++q) {
            float alo = __uint_as_float(pa[q] << 16);
            float ahi = __uint_as_float(pa[q] & 0xffff0000u);
            float blo = __uint_as_float(pb[q] << 16);
            float bhi = __uint_as_float(pb[q] & 0xffff0000u);
            float clo = __uint_as_float(pc[q] << 16);
            float chi = __uint_as_float(pc[q] & 0xffff0000u);
            s += alo * clo * blo;
            s += ahi * chi * bhi;
        }
    }

#pragma unroll
    for (int off = 8; off >= 1; off >>= 1)
        s += __shfl_xor(s, off);

    if (lane == 0)
        out[e] = 1.0f / (1.0f + __expf(-s));
}

extern "C" void kernel_launch(void* const* d_in, const int* in_sizes, int n_in,
                              void* d_out, int out_size, void* d_ws, size_t ws_size,
                              hipStream_t stream) {
    const float* h     = (const float*)d_in[0];
    const int*   u     = (const int*)  d_in[1];
    const int*   v     = (const int*)  d_in[2];
    const int*   etype = (const int*)  d_in[3];
    const float* rel   = (const float*)d_in[4];
    float* out = (float*)d_out;

    int n_edges = in_sizes[1];          // E = 250000
    int n_rel   = in_sizes[4];          // 8*384 = 3072

    uint32_t* hb = (uint32_t*)d_ws;                          // 76.8 MB bf16 h
    uint32_t* rb = (uint32_t*)((char*)d_ws + H_BF16_BYTES);  // 6 KB bf16 rel

    int n8_h = N_NODES_ELEMS / 8;       // 4,800,000 threads
    conv_kernel<<<(n8_h + 255) / 256, 256, 0, stream>>>(h, hb, n8_h);
    int n8_r = n_rel / 8;               // 384 threads
    conv_kernel<<<(n8_r + 255) / 256, 256, 0, stream>>>(rel, rb, n8_r);

    long long threads_total = (long long)n_edges * 16;
    int grid = (int)((threads_total + 255) / 256);
    distmult_kernel<<<grid, 256, 0, stream>>>(hb, rb, u, v, etype, out, n_edges);
}